// Round 15
// baseline (613.993 us; speedup 1.0000x reference)
//
#include <hip/hip_runtime.h>
#include <hip/hip_bf16.h>
#include <cstdint>
#include <cstddef>

typedef unsigned short u16;
typedef u16 u16x8 __attribute__((ext_vector_type(8)));
typedef u16 u16x4 __attribute__((ext_vector_type(4)));
typedef __bf16 bf16x8 __attribute__((ext_vector_type(8)));
typedef float f32x4 __attribute__((ext_vector_type(4)));

__device__ const unsigned short ADJ_MASK[12] = {
    95u, 575u, 2095u, 15u, 19u, 38u, 193u, 448u, 896u, 1794u, 3584u, 3076u};

__device__ __forceinline__ float b2f(u16 u) {
  union { unsigned int i; float f; } v;
  v.i = ((unsigned int)u) << 16;
  return v.f;
}
__device__ __forceinline__ u16 f2b(float f) {
  union { float f; unsigned int i; } v;
  v.f = f;
  unsigned int r = v.i + 0x7fffu + ((v.i >> 16) & 1u);
  return (u16)(r >> 16);
}

// global -> LDS direct (16B per lane). LDS dest must be linear in lane order.
#define GLOAD_LDS16(gsrc, ldst)                                         \
  __builtin_amdgcn_global_load_lds(                                     \
      (const __attribute__((address_space(1))) unsigned int*)(gsrc),    \
      (__attribute__((address_space(3))) unsigned int*)(ldst), 16, 0, 0)

__device__ __forceinline__ void build_anorm(float* An) {
  int t = threadIdx.x;
  if (t < 144) {
    int i = t / 12, j = t % 12;
    float di = (float)__popc((int)ADJ_MASK[i]);
    float dj = (float)__popc((int)ADJ_MASK[j]);
    An[t] = ((ADJ_MASK[i] >> j) & 1) ? (1.0f / sqrtf(di * dj)) : 0.0f;
  }
}

// -------- runtime dtype detector: block 0 -> x, block 1 -> W ----------------
__global__ void __launch_bounds__(256) k_detect2(const void* a, const void* b,
                                                 int* flags) {
  const unsigned int* w = (const unsigned int*)(blockIdx.x ? b : a);
  __shared__ int s;
  if (threadIdx.x == 0) s = 0;
  __syncthreads();
  int cnt = 0;
  for (int t = 0; t < 16; ++t) {
    unsigned int v = w[t * 256 + threadIdx.x];
    unsigned int e = (v >> 7) & 0xFFu;
    if (e != 0u && (e < 0x5Au || e > 0x89u)) ++cnt;
  }
  atomicAdd(&s, cnt);
  __syncthreads();
  if (threadIdx.x == 0) flags[blockIdx.x] = (s > 1024) ? 1 : 0;
}

// -------- all small vectors in ONE launch (dst segments are contiguous) ------
__global__ void __launch_bounds__(256) k_cvt_small(
    const void* b1, const void* b2, const void* b3, const void* inb,
    const void* outb, const void* lng, const void* lnb, u16* dst,
    const int* flag) {
  int idx = blockIdx.x * 256 + threadIdx.x;  // grid 9 -> 2304
  if (idx >= 2304) return;
  const void* src;
  int off = idx;
  if (idx < 256)       { src = b1; }
  else if (idx < 512)  { src = b2;   off = idx - 256; }
  else if (idx < 768)  { src = b3;   off = idx - 512; }
  else if (idx < 1536) { src = inb;  off = idx - 768; }
  else if (idx < 1792) { src = outb; off = idx - 1536; }
  else if (idx < 2048) { src = lng;  off = idx - 1792; }
  else                 { src = lnb;  off = idx - 2048; }
  dst[idx] = (*flag) ? f2b(((const float*)src)[off]) : ((const u16*)src)[off];
}

// -------- inw + outw convert in ONE launch (dst contiguous) ------------------
__global__ void __launch_bounds__(256) k_cvt_w(const void* inw,
                                               const void* outw, u16* dst,
                                               const int* flag) {
  int idx = blockIdx.x * 256 + threadIdx.x;  // grid 1024 -> 262144
  const void* src = (idx < 196608) ? inw : outw;
  int off = (idx < 196608) ? idx : idx - 196608;
  dst[idx] = (*flag) ? f2b(((const float*)src)[off]) : ((const u16*)src)[off];
}

// -------- W1,W2,W3 transpose+convert in ONE launch (dst contiguous) ----------
__global__ void __launch_bounds__(256) k_transpose3(const void* W1,
                                                    const void* W2,
                                                    const void* W3, u16* dst,
                                                    const int* flag) {
  int idx = blockIdx.x * 256 + threadIdx.x;  // grid 1024 -> 262144
  const void* src;
  int R, C, li = idx;
  if (idx < 131072)      { src = W1; R = 512; C = 256; }
  else if (idx < 196608) { src = W2; R = 256; C = 256; li = idx - 131072; }
  else                   { src = W3; R = 256; C = 256; li = idx - 196608; }
  int c = li / R, r = li - c * R;
  u16 v = (*flag) ? f2b(((const float*)src)[r * C + c])
                  : ((const u16*)src)[r * C + c];
  dst[(idx - li) + c * R + r] = v;
}

// ------ MFMA GEMM core, 96x256 tile (round-5, proven) -- pool only -----------
__device__ __forceinline__ void gemm_core(const void* __restrict__ A, int lda,
                                          int isf32,
                                          const u16* __restrict__ Bt,
                                          u16* As, u16* Bs,
                                          long m0, long n0, int K,
                                          f32x4 acc[6][4]) {
  const int tid = threadIdx.x;
  const int wave = tid >> 6, lane = tid & 63;
  const int q = lane >> 4, r16 = lane & 15;
  f32x4 zero = {0.f, 0.f, 0.f, 0.f};
#pragma unroll
  for (int a = 0; a < 6; ++a)
#pragma unroll
    for (int b = 0; b < 4; ++b) acc[a][b] = zero;

  for (int k0 = 0; k0 < K; k0 += 64) {
    if (isf32) {
      const float* Af = (const float*)A;
#pragma unroll
      for (int i = 0; i < 3; ++i) {
        int idx = i * 256 + tid;
        int rr = idx >> 3, cg = idx & 7;
        const float* sp = Af + (m0 + rr) * (long)lda + k0 + cg * 8;
        u16x8 t;
#pragma unroll
        for (int u = 0; u < 8; ++u) t[u] = f2b(sp[u]);
        *(u16x8*)(As + rr * 64 + ((cg ^ (rr & 7)) << 3)) = t;
      }
    } else {
      const u16* Ab = (const u16*)A;
#pragma unroll
      for (int i = 0; i < 3; ++i) {
        int c = i * 256 + tid;
        int rr = c >> 3, s = c & 7;
        GLOAD_LDS16(Ab + (m0 + rr) * (long)lda + k0 + ((s ^ (rr & 7)) << 3),
                    As + c * 8);
      }
    }
#pragma unroll
    for (int i = 0; i < 8; ++i) {
      int c = i * 256 + tid;
      int rr = c >> 3, s = c & 7;
      GLOAD_LDS16(Bt + (n0 + rr) * (long)K + k0 + ((s ^ (rr & 7)) << 3),
                  Bs + c * 8);
    }
    __syncthreads();
#pragma unroll
    for (int ks = 0; ks < 64; ks += 32) {
      const int ck = q + (ks >> 3);
      bf16x8 af[6], bfv[4];
#pragma unroll
      for (int rb = 0; rb < 6; ++rb) {
        int row = rb * 16 + r16;
        af[rb] = *(const bf16x8*)(As + row * 64 + ((ck ^ (row & 7)) << 3));
      }
#pragma unroll
      for (int cb = 0; cb < 4; ++cb) {
        int row = (wave * 4 + cb) * 16 + r16;
        bfv[cb] = *(const bf16x8*)(Bs + row * 64 + ((ck ^ (row & 7)) << 3));
      }
#pragma unroll
      for (int rb = 0; rb < 6; ++rb)
#pragma unroll
        for (int cb = 0; cb < 4; ++cb)
          acc[rb][cb] = __builtin_amdgcn_mfma_f32_16x16x32_bf16(
              af[rb], bfv[cb], acc[rb][cb], 0, 0, 0);
    }
    __syncthreads();
  }
}

// ------ MFMA GEMM core, 96x128 tile (round-6, proven; single-buffer) --------
__device__ __forceinline__ void gemm_core128(const void* __restrict__ A,
                                             int lda, int isf32,
                                             const u16* __restrict__ Bt,
                                             u16* As, u16* Bs,
                                             long m0, long n0, int K,
                                             f32x4 acc[6][2]) {
  const int tid = threadIdx.x;
  const int wave = tid >> 6, lane = tid & 63;
  const int q = lane >> 4, r16 = lane & 15;
  f32x4 zero = {0.f, 0.f, 0.f, 0.f};
#pragma unroll
  for (int a = 0; a < 6; ++a)
#pragma unroll
    for (int b = 0; b < 2; ++b) acc[a][b] = zero;

  for (int k0 = 0; k0 < K; k0 += 64) {
    if (isf32) {
      const float* Af = (const float*)A;
#pragma unroll
      for (int i = 0; i < 3; ++i) {
        int idx = i * 256 + tid;
        int rr = idx >> 3, cg = idx & 7;
        const float* sp = Af + (m0 + rr) * (long)lda + k0 + cg * 8;
        u16x8 t;
#pragma unroll
        for (int u = 0; u < 8; ++u) t[u] = f2b(sp[u]);
        *(u16x8*)(As + rr * 64 + ((cg ^ (rr & 7)) << 3)) = t;
      }
    } else {
      const u16* Ab = (const u16*)A;
#pragma unroll
      for (int i = 0; i < 3; ++i) {
        int c = i * 256 + tid;
        int rr = c >> 3, s = c & 7;
        GLOAD_LDS16(Ab + (m0 + rr) * (long)lda + k0 + ((s ^ (rr & 7)) << 3),
                    As + c * 8);
      }
    }
#pragma unroll
    for (int i = 0; i < 4; ++i) {       // 128 rows x 8 chunks = 1024
      int c = i * 256 + tid;
      int rr = c >> 3, s = c & 7;
      GLOAD_LDS16(Bt + (n0 + rr) * (long)K + k0 + ((s ^ (rr & 7)) << 3),
                  Bs + c * 8);
    }
    __syncthreads();
#pragma unroll
    for (int ks = 0; ks < 64; ks += 32) {
      const int ck = q + (ks >> 3);
      bf16x8 af[6], bfv[2];
#pragma unroll
      for (int rb = 0; rb < 6; ++rb) {
        int row = rb * 16 + r16;
        af[rb] = *(const bf16x8*)(As + row * 64 + ((ck ^ (row & 7)) << 3));
      }
#pragma unroll
      for (int cb = 0; cb < 2; ++cb) {
        int row = (wave * 2 + cb) * 16 + r16;
        bfv[cb] = *(const bf16x8*)(Bs + row * 64 + ((ck ^ (row & 7)) << 3));
      }
#pragma unroll
      for (int rb = 0; rb < 6; ++rb)
#pragma unroll
        for (int cb = 0; cb < 2; ++cb)
          acc[rb][cb] = __builtin_amdgcn_mfma_f32_16x16x32_bf16(
              af[rb], bfv[cb], acc[rb][cb], 0, 0, 0);
    }
    __syncthreads();
  }
}

// ---- GEMM fused with lead-mix + bias + relu (96x128 tile, 4 blk/CU) --------
// Grid: blockIdx.x = n-tile (FASTEST), blockIdx.y = m-tile. Measured (r10/r13):
// n-fastest + 4 blk/CU keeps same-A-panel blocks concurrent so their A-reads
// merge (FETCH ~= 1x A). m-fastest (r10) or 5 blk/CU (r13) both re-duplicate
// the A fetch (FETCH ~= 2x A) and regress. Do not change either knob.
template <int K>
__global__ void __launch_bounds__(256, 4) k_gemm_mix(const void* __restrict__ A,
                                                     int lda,
                                                     const u16* __restrict__ Bt,
                                                     const u16* __restrict__ bias,
                                                     u16* __restrict__ C,
                                                     const int* aflag) {
  __shared__ __align__(16) char smraw[28672];
  __shared__ float An[144];
  u16* As = (u16*)smraw;            // 96*64  = 12288 B
  u16* Bs = As + 96 * 64;           // 128*64 = 16384 B
  u16* Y = (u16*)smraw;             // 96*136 u16 = 26112 B (union, after core)
  build_anorm(An);
  f32x4 acc[6][2];
  const long n0 = (long)blockIdx.x * 128;
  const long m0 = (long)blockIdx.y * 96;
  int isf32 = aflag ? *aflag : 0;
  gemm_core128(A, lda, isf32, Bt, As, Bs, m0, n0, K, acc);
  const int tid = threadIdx.x;
  const int wave = tid >> 6, lane = tid & 63;
  const int q = lane >> 4, r16 = lane & 15;
#pragma unroll
  for (int cb = 0; cb < 2; ++cb) {
    int col = (wave * 2 + cb) * 16 + r16;    // 0..127 local
#pragma unroll
    for (int rb = 0; rb < 6; ++rb)
#pragma unroll
      for (int rr = 0; rr < 4; ++rr) {
        int row = rb * 16 + q * 4 + rr;
        Y[row * 136 + col] = f2b(acc[rb][cb][rr]);  // raw G (bias after mix)
      }
  }
  __syncthreads();
  // mix: 8 samples x 32 threads; each thread 4 local cols
  const int s = tid >> 5, cg = tid & 31;
  float bb4[4];
#pragma unroll
  for (int u = 0; u < 4; ++u) bb4[u] = b2f(bias[n0 + cg * 4 + u]);
  float xn[12][4];
#pragma unroll
  for (int j = 0; j < 12; ++j) {
    u16x4 yv = *(const u16x4*)(Y + (s * 12 + j) * 136 + cg * 4);
#pragma unroll
    for (int u = 0; u < 4; ++u) xn[j][u] = b2f(yv[u]);
  }
  const long cbase = m0 * 256;
#pragma unroll
  for (int i = 0; i < 12; ++i) {
    float o[4] = {bb4[0], bb4[1], bb4[2], bb4[3]};
    for (int j = 0; j < 12; ++j) {
      float c = An[i * 12 + j];
      if (c != 0.0f) {
#pragma unroll
        for (int u = 0; u < 4; ++u) o[u] += c * xn[j][u];
      }
    }
    u16x4 ov;
#pragma unroll
    for (int u = 0; u < 4; ++u) ov[u] = f2b(fmaxf(o[u], 0.0f));
    *(u16x4*)(C + cbase + (long)(s * 12 + i) * 256 + n0 + cg * 4) = ov;
  }
}

// ---------------- generic GEMM + bias, bf16 out ------------------------------
// 96x128 tile; blockIdx.x = n-tile (fastest), blockIdx.y = m-tile (see above).
template <bool BIAS, int K>
__global__ void __launch_bounds__(256, 4) k_gemm(const void* __restrict__ A,
                                                 int lda,
                                                 const u16* __restrict__ Bt,
                                                 const u16* __restrict__ bias,
                                                 u16* __restrict__ C,
                                                 int Ntot,
                                                 const int* aflag) {
  __shared__ u16 As[96 * 64];
  __shared__ u16 Bs[128 * 64];
  f32x4 acc[6][2];
  const long n0 = (long)blockIdx.x * 128;
  const long m0 = (long)blockIdx.y * 96;
  int isf32 = aflag ? *aflag : 0;
  gemm_core128(A, lda, isf32, Bt, As, Bs, m0, n0, K, acc);
  const int tid = threadIdx.x;
  const int wave = tid >> 6, lane = tid & 63;
  const int q = lane >> 4, r16 = lane & 15;
#pragma unroll
  for (int cb = 0; cb < 2; ++cb) {
    long col = n0 + (wave * 2 + cb) * 16 + r16;
    float bvv = BIAS ? b2f(bias[col]) : 0.0f;
#pragma unroll
    for (int rb = 0; rb < 6; ++rb) {
#pragma unroll
      for (int rr = 0; rr < 4; ++rr) {
        long row = m0 + rb * 16 + q * 4 + rr;
        C[row * (long)Ntot + col] = f2b(acc[rb][cb][rr] + bvv);
      }
    }
  }
}

// ---------------- attention: u16x8 bulk loads (round-12-verified) ------------
__global__ void __launch_bounds__(256) k_attn(u16* __restrict__ QKV) {
  __shared__ u16 T[12 * 768];
  __shared__ float Sc[4][12][12];
  const int tid = threadIdx.x;
  const long base = (long)blockIdx.x * (12 * 768);
#pragma unroll
  for (int i = 0; i < 4; ++i) {
    int idx = i * 256 + tid;
    *(u16x8*)(T + idx * 8) = *(const u16x8*)(QKV + base + idx * 8);
  }
  {
    int off = 8192 + tid * 4;
    *(u16x4*)(T + off) = *(const u16x4*)(QKV + base + off);
  }
  __syncthreads();
  for (int p = tid; p < 576; p += 256) {
    int h = p / 144, r = p % 144, i = r / 12, j = r % 12;
    const u16* qp = T + i * 768 + h * 64;
    const u16* kp = T + j * 768 + 256 + h * 64;
    float s = 0.f;
#pragma unroll
    for (int dv = 0; dv < 8; ++dv) {
      u16x8 qv = *(const u16x8*)(qp + dv * 8);
      u16x8 kv = *(const u16x8*)(kp + dv * 8);
#pragma unroll
      for (int u = 0; u < 8; ++u) s += b2f(qv[u]) * b2f(kv[u]);
    }
    Sc[h][i][j] = s * 0.125f;
  }
  __syncthreads();
  if (tid < 48) {
    int h = tid / 12, i = tid % 12;
    float m = -1e30f;
#pragma unroll
    for (int j = 0; j < 12; ++j) m = fmaxf(m, Sc[h][i][j]);
    float e[12];
    float ssum = 0.f;
#pragma unroll
    for (int j = 0; j < 12; ++j) {
      e[j] = __expf(Sc[h][i][j] - m);
      ssum += e[j];
    }
    float inv = 1.0f / ssum;
#pragma unroll
    for (int j = 0; j < 12; ++j) Sc[h][i][j] = e[j] * inv;
  }
  __syncthreads();
  {
    int h = tid >> 6;
    int d = tid & 63;
    float vv[12];
#pragma unroll
    for (int j = 0; j < 12; ++j) vv[j] = b2f(T[j * 768 + 512 + h * 64 + d]);
#pragma unroll
    for (int i = 0; i < 12; ++i) {
      float o = 0.f;
#pragma unroll
      for (int j = 0; j < 12; ++j) o += Sc[h][i][j] * vv[j];
      QKV[base + i * 768 + h * 64 + d] = f2b(o);
    }
  }
}

// --------- residual + layernorm + lead-mix (u16x8 staging; FP order same) ----
__global__ void __launch_bounds__(256) k_resid_ln_mix(
    const u16* __restrict__ H, const u16* __restrict__ Oa,
    const u16* __restrict__ g, const u16* __restrict__ bb,
    u16* __restrict__ out) {
  __shared__ float Xn[12 * 256];
  __shared__ float An[144];
  __shared__ float mu[12], rs[12];
  build_anorm(An);
  const int tid = threadIdx.x;
  const long baseH = (long)blockIdx.x * 3072;
  const long baseO = (long)blockIdx.x * 9216;
#pragma unroll
  for (int i = 0; i < 2; ++i) {
    int idx = i * 256 + tid;        // 384 vec8 groups (Xn contents identical)
    if (idx < 384) {
      int row = idx >> 5, c8 = idx & 31;
      u16x8 hv = *(const u16x8*)(H + baseH + idx * 8);
      u16x8 ov = *(const u16x8*)(Oa + baseO + row * 768 + c8 * 8);
#pragma unroll
      for (int u = 0; u < 8; ++u) Xn[idx * 8 + u] = b2f(hv[u]) + b2f(ov[u]);
    }
  }
  __syncthreads();
  {
    int wave = tid >> 6, lane = tid & 63;
    for (int rr = wave; rr < 12; rr += 4) {
      float s = 0.f, s2 = 0.f;
#pragma unroll
      for (int u = 0; u < 4; ++u) {
        float xv = Xn[rr * 256 + u * 64 + lane];
        s += xv;
        s2 += xv * xv;
      }
#pragma unroll
      for (int off = 32; off > 0; off >>= 1) {
        s += __shfl_down(s, off, 64);
        s2 += __shfl_down(s2, off, 64);
      }
      if (lane == 0) {
        float m = s * (1.0f / 256.0f);
        float var = s2 * (1.0f / 256.0f) - m * m;
        mu[rr] = m;
        rs[rr] = rsqrtf(var + 1e-5f);
      }
    }
  }
  __syncthreads();
  {
    float gv = b2f(g[tid]);
    float bv = b2f(bb[tid]);
    float xn[12];
#pragma unroll
    for (int i = 0; i < 12; ++i) {
      float x = Xn[i * 256 + tid];
      xn[i] = (x - mu[i]) * rs[i] * gv + bv;
    }
#pragma unroll
    for (int i = 0; i < 12; ++i) {
      float o = 0.f;
#pragma unroll
      for (int j = 0; j < 12; ++j) o += An[i * 12 + j] * xn[j];
      out[baseH + i * 256 + tid] = f2b(o);
    }
  }
}

// ------- fused attention mega-kernel -- FALLBACK path (small ws), verbatim ---
__global__ void __launch_bounds__(256) k_attn_mega(
    u16* __restrict__ H, const u16* __restrict__ inw,
    const u16* __restrict__ inb, const u16* __restrict__ outw,
    const u16* __restrict__ outb, const u16* __restrict__ lng,
    const u16* __restrict__ lnb) {
  __shared__ u16 Hs[32 * 264];
  __shared__ u16 Qs[32 * 264];
  __shared__ u16 KVs[24 * 512];
  __shared__ float Sc[4][2][12][12];
  __shared__ float An[144];
  __shared__ float mu[24], rs[24];
  const int tid = threadIdx.x;
  const int wave = tid >> 6, lane = tid & 63;
  const int q = lane >> 4, r16 = lane & 15;
  build_anorm(An);
  const long base = (long)blockIdx.x * 6144;
#pragma unroll
  for (int i = 0; i < 3; ++i) {
    int idx = i * 256 + tid;
    int rr = idx >> 5, cg = idx & 31;
    *(u16x8*)(Hs + rr * 264 + cg * 8) = *(const u16x8*)(H + base + idx * 8);
  }
  {
    int rr = 24 + (tid >> 5), cg = tid & 31;
    u16x8 z = {0, 0, 0, 0, 0, 0, 0, 0};
    *(u16x8*)(Hs + rr * 264 + cg * 8) = z;
  }
  __syncthreads();
  {
    f32x4 acc[2][12];
    f32x4 zero = {0.f, 0.f, 0.f, 0.f};
#pragma unroll
    for (int rb = 0; rb < 2; ++rb)
#pragma unroll
      for (int c = 0; c < 12; ++c) acc[rb][c] = zero;
    for (int k0 = 0; k0 < 256; k0 += 32) {
      bf16x8 af[2];
#pragma unroll
      for (int rb = 0; rb < 2; ++rb)
        af[rb] = *(const bf16x8*)(Hs + (rb * 16 + r16) * 264 + k0 + q * 8);
#pragma unroll
      for (int c = 0; c < 12; ++c) {
        bf16x8 bf = *(const bf16x8*)(inw + (long)((wave * 12 + c) * 16 + r16) * 256 + k0 + q * 8);
#pragma unroll
        for (int rb = 0; rb < 2; ++rb)
          acc[rb][c] = __builtin_amdgcn_mfma_f32_16x16x32_bf16(af[rb], bf, acc[rb][c], 0, 0, 0);
      }
    }
#pragma unroll
    for (int c = 0; c < 12; ++c) {
      int col = (wave * 12 + c) * 16 + r16;
      float bv = b2f(inb[col]);
#pragma unroll
      for (int rb = 0; rb < 2; ++rb)
#pragma unroll
        for (int rr2 = 0; rr2 < 4; ++rr2) {
          int row = rb * 16 + q * 4 + rr2;
          float v = acc[rb][c][rr2] + bv;
          if (col < 256) Qs[row * 264 + col] = f2b(v);
          else if (row < 24) KVs[row * 512 + col - 256] = f2b(v);
        }
    }
  }
  __syncthreads();
  {
    int h = wave;
#pragma unroll
    for (int t = 0; t < 5; ++t) {
      int p = t * 64 + lane;
      if (p < 288) {
        int s = p / 144, r = p - s * 144, i = r / 12, j = r - i * 12;
        const u16* qp = Qs + (s * 12 + i) * 264 + h * 64;
        const u16* kp = KVs + (s * 12 + j) * 512 + h * 64;
        float dot = 0.f;
#pragma unroll
        for (int dv = 0; dv < 8; ++dv) {
          u16x8 qv = *(const u16x8*)(qp + dv * 8);
          u16x8 kv = *(const u16x8*)(kp + dv * 8);
#pragma unroll
          for (int u = 0; u < 8; ++u) dot += b2f(qv[u]) * b2f(kv[u]);
        }
        Sc[h][s][i][j] = dot * 0.125f;
      }
    }
  }
  __syncthreads();
  if (lane < 24) {
    int h = wave, s = lane / 12, i = lane - (lane / 12) * 12;
    float m = -1e30f;
#pragma unroll
    for (int j = 0; j < 12; ++j) m = fmaxf(m, Sc[h][s][i][j]);
    float e[12];
    float ssum = 0.f;
#pragma unroll
    for (int j = 0; j < 12; ++j) {
      e[j] = __expf(Sc[h][s][i][j] - m);
      ssum += e[j];
    }
    float inv = 1.0f / ssum;
#pragma unroll
    for (int j = 0; j < 12; ++j) Sc[h][s][i][j] = e[j] * inv;
  }
  __syncthreads();
  {
    int h = wave, d = lane;
    for (int si = 0; si < 24; ++si) {
      int s = si / 12;
      float o = 0.f;
#pragma unroll
      for (int j = 0; j < 12; ++j)
        o += Sc[h][s][si - s * 12][j] * b2f(KVs[(s * 12 + j) * 512 + 256 + h * 64 + d]);
      Qs[si * 264 + h * 64 + d] = f2b(o);
    }
  }
  __syncthreads();
  {
    f32x4 acc[2][4];
    f32x4 zero = {0.f, 0.f, 0.f, 0.f};
#pragma unroll
    for (int rb = 0; rb < 2; ++rb)
#pragma unroll
      for (int cb = 0; cb < 4; ++cb) acc[rb][cb] = zero;
    for (int k0 = 0; k0 < 256; k0 += 32) {
      bf16x8 af[2];
#pragma unroll
      for (int rb = 0; rb < 2; ++rb)
        af[rb] = *(const bf16x8*)(Qs + (rb * 16 + r16) * 264 + k0 + q * 8);
#pragma unroll
      for (int cb = 0; cb < 4; ++cb) {
        bf16x8 bf = *(const bf16x8*)(outw + (long)((wave * 4 + cb) * 16 + r16) * 256 + k0 + q * 8);
#pragma unroll
        for (int rb = 0; rb < 2; ++rb)
          acc[rb][cb] = __builtin_amdgcn_mfma_f32_16x16x32_bf16(af[rb], bf, acc[rb][cb], 0, 0, 0);
      }
    }
#pragma unroll
    for (int cb = 0; cb < 4; ++cb) {
      int col = (wave * 4 + cb) * 16 + r16;
      float ob = b2f(outb[col]);
#pragma unroll
      for (int rb = 0; rb < 2; ++rb)
#pragma unroll
        for (int rr2 = 0; rr2 < 4; ++rr2) {
          int row = rb * 16 + q * 4 + rr2;
          if (row < 24) {
            float x = acc[rb][cb][rr2] + ob + b2f(Hs[row * 264 + col]);
            Hs[row * 264 + col] = f2b(x);
          }
        }
    }
  }
  __syncthreads();
  {
    for (int rr2 = wave * 6; rr2 < wave * 6 + 6; ++rr2) {
      float s1 = 0.f, s2 = 0.f;
#pragma unroll
      for (int u = 0; u < 4; ++u) {
        float xv = b2f(Hs[rr2 * 264 + u * 64 + lane]);
        s1 += xv;
        s2 += xv * xv;
      }
#pragma unroll
      for (int off = 32; off > 0; off >>= 1) {
        s1 += __shfl_down(s1, off, 64);
        s2 += __shfl_down(s2, off, 64);
      }
      if (lane == 0) {
        float m = s1 * (1.0f / 256.0f);
        mu[rr2] = m;
        rs[rr2] = rsqrtf(s2 * (1.0f / 256.0f) - m * m + 1e-5f);
      }
    }
  }
  __syncthreads();
  {
    float gvv = b2f(lng[tid]);
    float bvv = b2f(lnb[tid]);
#pragma unroll
    for (int s = 0; s < 2; ++s) {
      float xn[12];
#pragma unroll
      for (int j = 0; j < 12; ++j) {
        int row = s * 12 + j;
        xn[j] = (b2f(Hs[row * 264 + tid]) - mu[row]) * rs[row] * gvv + bvv;
      }
#pragma unroll
      for (int i = 0; i < 12; ++i) {
        float o = 0.f;
#pragma unroll
        for (int j = 0; j < 12; ++j) o += An[i * 12 + j] * xn[j];
        H[base + (s * 12 + i) * 256 + tid] = f2b(o);
      }
    }
  }
}

// ---------- final GEMM + bias + attention-pooling; OUTPUT = float32 ----------
// ONLY change this round: (256,2) -> (256,3). LDS 50688*3 = 152KB <= 160KB;
// VGPR must fit ~170/wave (acc 96 + ~74 staging/addr) -- allocator-shaved.
__global__ void __launch_bounds__(256, 3) k_gemm_pool(const u16* __restrict__ A,
                                                      const u16* __restrict__ Bt,
                                                      const u16* __restrict__ bias,
                                                      float* __restrict__ out) {
  __shared__ __align__(16) char smraw[50688];
  __shared__ float rowsum[96];
  __shared__ float wsm[96];
  u16* As = (u16*)smraw;            // 96*64
  u16* Bs = As + 96 * 64;           // 256*64  (total 45056 B < 50688)
  u16* Y = (u16*)smraw;             // 96*264 after final barrier
  f32x4 acc[6][4];
  const long m0 = (long)blockIdx.x * 96;
  gemm_core(A, 256, 0, Bt, As, Bs, m0, 0, 256, acc);
  const int tid = threadIdx.x;
  const int wave = tid >> 6, lane = tid & 63;
  const int q = lane >> 4, r16 = lane & 15;
#pragma unroll
  for (int cb = 0; cb < 4; ++cb) {
    int col = (wave * 4 + cb) * 16 + r16;
    float bvv = b2f(bias[col]);
#pragma unroll
    for (int rb = 0; rb < 6; ++rb)
#pragma unroll
      for (int rr = 0; rr < 4; ++rr) {
        int row = rb * 16 + q * 4 + rr;
        Y[row * 264 + col] = f2b(acc[rb][cb][rr] + bvv);
      }
  }
  __syncthreads();
  for (int row = wave; row < 96; row += 4) {
    float s = 0.f;
#pragma unroll
    for (int u = 0; u < 4; ++u) s += b2f(Y[row * 264 + u * 64 + lane]);
#pragma unroll
    for (int off = 32; off > 0; off >>= 1) s += __shfl_down(s, off, 64);
    if (lane == 0) rowsum[row] = s;
  }
  __syncthreads();
  if (tid < 8) {
    float m = -1e30f;
#pragma unroll
    for (int l = 0; l < 12; ++l) m = fmaxf(m, rowsum[tid * 12 + l]);
    float e[12];
    float ssum = 0.f;
#pragma unroll
    for (int l = 0; l < 12; ++l) {
      e[l] = __expf((rowsum[tid * 12 + l] - m) * (1.0f / 256.0f));
      ssum += e[l];
    }
    float inv = 1.0f / ssum;
#pragma unroll
    for (int l = 0; l < 12; ++l) wsm[tid * 12 + l] = e[l] * inv;
  }
  __syncthreads();
  {
    int s = tid >> 5, cg = tid & 31;
    float wa[8], mx[8];
#pragma unroll
    for (int u = 0; u < 8; ++u) {
      wa[u] = 0.f;
      mx[u] = -1e30f;
    }
#pragma unroll
    for (int l = 0; l < 12; ++l) {
      float w = wsm[s * 12 + l];
      u16x8 yv = *(const u16x8*)(Y + (s * 12 + l) * 264 + cg * 8);
#pragma unroll
      for (int u = 0; u < 8; ++u) {
        float y = b2f(yv[u]);
        wa[u] += w * y;
        mx[u] = fmaxf(mx[u], y);
      }
    }
    long ob = ((long)blockIdx.x * 8 + s) * 512;
#pragma unroll
    for (int u = 0; u < 8; ++u) {
      out[ob + cg * 8 + u] = wa[u];
      out[ob + 256 + cg * 8 + u] = mx[u];
    }
  }
}

extern "C" void kernel_launch(void* const* d_in, const int* in_sizes, int n_in,
                              void* d_out, int out_size, void* d_ws,
                              size_t ws_size, hipStream_t stream) {
  (void)in_sizes; (void)n_in; (void)out_size;
  const void* x    = d_in[0];
  const void* W1   = d_in[1];
  const void* b1   = d_in[2];
  const void* W2   = d_in[3];
  const void* b2   = d_in[4];
  const void* W3   = d_in[5];
  const void* b3   = d_in[6];
  const void* inw  = d_in[7];
  const void* inb  = d_in[8];
  const void* outw = d_in[9];
  const void* outb = d_in[10];
  const void* lng  = d_in[11];
  const void* lnb  = d_in[12];
  float* out = (float*)d_out;

  u16* ws16 = (u16*)d_ws;
  int* flags = (int*)d_ws;                 // flags[0]=x dtype, flags[1]=W dtype
  u16* W1T    = ws16 + 64;
  u16* W2T    = W1T + 131072;
  u16* W3T    = W2T + 65536;
  u16* inw_b  = W3T + 65536;
  u16* outw_b = inw_b + 196608;
  u16* b1b    = outw_b + 65536;
  u16* b2b    = b1b + 256;
  u16* b3b    = b2b + 256;
  u16* inbb   = b3b + 256;
  u16* outbb  = inbb + 768;
  u16* lngb   = outbb + 256;
  u16* lnbb   = lngb + 256;
  u16* BUF    = lnbb + 256;            // 25165824 elems (H2 / HL)
  u16* QKV    = BUF + 25165824L;       // 75497472 elems (pipeline A only)
  const size_t NEED_A = (size_t)(QKV + 75497472L - ws16) * 2;  // ~202.4 MB

  k_detect2<<<2, 256, 0, stream>>>(x, W1, flags);

  k_cvt_small<<<9, 256, 0, stream>>>(b1, b2, b3, inb, outb, lng, lnb, b1b,
                                     flags + 1);
  k_cvt_w<<<1024, 256, 0, stream>>>(inw, outw, inw_b, flags + 1);
  k_transpose3<<<1024, 256, 0, stream>>>(W1, W2, W3, W1T, flags + 1);

  if (ws_size >= NEED_A) {
    u16* H1 = QKV;  // QKV region is dead until the QKV projection; use as
                    // scratch so gemm_mix never writes a buffer it reads.
    // H1 = relu(A.(x@W1)+b1)   [mix fused in epilogue; n-tile fastest]
    k_gemm_mix<512><<<dim3(2, 1024), 256, 0, stream>>>(x, 512, W1T, b1b, H1, flags);
    // H2 = relu(A.(H1@W2)+b2) -> BUF
    k_gemm_mix<256><<<dim3(2, 1024), 256, 0, stream>>>(H1, 256, W2T, b2b, BUF, nullptr);
    // QKV = H2 @ in_w^T + in_b   (overwrites dead H1 scratch)
    k_gemm<true, 256><<<dim3(6, 1024), 256, 0, stream>>>(BUF, 256, inw_b, inbb, QKV, 768, nullptr);
    // attention, O -> Q slots (in place, per-block LDS-buffered)
    k_attn<<<8192, 256, 0, stream>>>(QKV);
    // O2 = O @ out_w^T + out_b -> K slots of QKV (disjoint from Q-slot reads)
    k_gemm<true, 256><<<dim3(2, 1024), 256, 0, stream>>>(QKV, 768, outw_b, outbb, QKV + 256, 768, nullptr);
    // HL = A.( LN(H2 + O2) ), in place into BUF  (round-6 FP order)
    k_resid_ln_mix<<<8192, 256, 0, stream>>>(BUF, QKV + 256, lngb, lnbb, BUF);
  } else {
    // Fallback (never taken in practice: ws has always been >= NEED_A).
    k_gemm_mix<512><<<dim3(2, 1024), 256, 0, stream>>>(x, 512, W1T, b1b, BUF, flags);
    k_gemm_mix<256><<<dim3(2, 1024), 256, 0, stream>>>(BUF, 256, W2T, b2b, BUF, nullptr);
    k_attn_mega<<<4096, 256, 0, stream>>>(BUF, inw_b, inbb, outw_b, outbb, lngb, lnbb);
  }
  // out = pool( HL@W3 + b3 )  -- float32 output
  k_gemm_pool<<<1024, 256, 0, stream>>>(BUF, W3T, b3b, out);
}

// Round 16
// 596.825 us; speedup vs baseline: 1.0288x; 1.0288x over previous
//
#include <hip/hip_runtime.h>
#include <hip/hip_bf16.h>
#include <cstdint>
#include <cstddef>

typedef unsigned short u16;
typedef u16 u16x8 __attribute__((ext_vector_type(8)));
typedef u16 u16x4 __attribute__((ext_vector_type(4)));
typedef __bf16 bf16x8 __attribute__((ext_vector_type(8)));
typedef float f32x4 __attribute__((ext_vector_type(4)));

__device__ const unsigned short ADJ_MASK[12] = {
    95u, 575u, 2095u, 15u, 19u, 38u, 193u, 448u, 896u, 1794u, 3584u, 3076u};

__device__ __forceinline__ float b2f(u16 u) {
  union { unsigned int i; float f; } v;
  v.i = ((unsigned int)u) << 16;
  return v.f;
}
__device__ __forceinline__ u16 f2b(float f) {
  union { float f; unsigned int i; } v;
  v.f = f;
  unsigned int r = v.i + 0x7fffu + ((v.i >> 16) & 1u);
  return (u16)(r >> 16);
}

// global -> LDS direct (16B per lane). LDS dest must be linear in lane order.
#define GLOAD_LDS16(gsrc, ldst)                                         \
  __builtin_amdgcn_global_load_lds(                                     \
      (const __attribute__((address_space(1))) unsigned int*)(gsrc),    \
      (__attribute__((address_space(3))) unsigned int*)(ldst), 16, 0, 0)

__device__ __forceinline__ void build_anorm(float* An) {
  int t = threadIdx.x;
  if (t < 144) {
    int i = t / 12, j = t % 12;
    float di = (float)__popc((int)ADJ_MASK[i]);
    float dj = (float)__popc((int)ADJ_MASK[j]);
    An[t] = ((ADJ_MASK[i] >> j) & 1) ? (1.0f / sqrtf(di * dj)) : 0.0f;
  }
}

// -------- runtime dtype detector: block 0 -> x, block 1 -> W ----------------
__global__ void __launch_bounds__(256) k_detect2(const void* a, const void* b,
                                                 int* flags) {
  const unsigned int* w = (const unsigned int*)(blockIdx.x ? b : a);
  __shared__ int s;
  if (threadIdx.x == 0) s = 0;
  __syncthreads();
  int cnt = 0;
  for (int t = 0; t < 16; ++t) {
    unsigned int v = w[t * 256 + threadIdx.x];
    unsigned int e = (v >> 7) & 0xFFu;
    if (e != 0u && (e < 0x5Au || e > 0x89u)) ++cnt;
  }
  atomicAdd(&s, cnt);
  __syncthreads();
  if (threadIdx.x == 0) flags[blockIdx.x] = (s > 1024) ? 1 : 0;
}

// -------- all small vectors in ONE launch (dst segments are contiguous) ------
__global__ void __launch_bounds__(256) k_cvt_small(
    const void* b1, const void* b2, const void* b3, const void* inb,
    const void* outb, const void* lng, const void* lnb, u16* dst,
    const int* flag) {
  int idx = blockIdx.x * 256 + threadIdx.x;  // grid 9 -> 2304
  if (idx >= 2304) return;
  const void* src;
  int off = idx;
  if (idx < 256)       { src = b1; }
  else if (idx < 512)  { src = b2;   off = idx - 256; }
  else if (idx < 768)  { src = b3;   off = idx - 512; }
  else if (idx < 1536) { src = inb;  off = idx - 768; }
  else if (idx < 1792) { src = outb; off = idx - 1536; }
  else if (idx < 2048) { src = lng;  off = idx - 1792; }
  else                 { src = lnb;  off = idx - 2048; }
  dst[idx] = (*flag) ? f2b(((const float*)src)[off]) : ((const u16*)src)[off];
}

// -------- inw + outw convert in ONE launch (dst contiguous) ------------------
__global__ void __launch_bounds__(256) k_cvt_w(const void* inw,
                                               const void* outw, u16* dst,
                                               const int* flag) {
  int idx = blockIdx.x * 256 + threadIdx.x;  // grid 1024 -> 262144
  const void* src = (idx < 196608) ? inw : outw;
  int off = (idx < 196608) ? idx : idx - 196608;
  dst[idx] = (*flag) ? f2b(((const float*)src)[off]) : ((const u16*)src)[off];
}

// -------- W1,W2,W3 transpose+convert in ONE launch (dst contiguous) ----------
__global__ void __launch_bounds__(256) k_transpose3(const void* W1,
                                                    const void* W2,
                                                    const void* W3, u16* dst,
                                                    const int* flag) {
  int idx = blockIdx.x * 256 + threadIdx.x;  // grid 1024 -> 262144
  const void* src;
  int R, C, li = idx;
  if (idx < 131072)      { src = W1; R = 512; C = 256; }
  else if (idx < 196608) { src = W2; R = 256; C = 256; li = idx - 131072; }
  else                   { src = W3; R = 256; C = 256; li = idx - 196608; }
  int c = li / R, r = li - c * R;
  u16 v = (*flag) ? f2b(((const float*)src)[r * C + c])
                  : ((const u16*)src)[r * C + c];
  dst[(idx - li) + c * R + r] = v;
}

// ------ MFMA GEMM core, 96x256 tile (round-5, proven) -- pool only -----------
__device__ __forceinline__ void gemm_core(const void* __restrict__ A, int lda,
                                          int isf32,
                                          const u16* __restrict__ Bt,
                                          u16* As, u16* Bs,
                                          long m0, long n0, int K,
                                          f32x4 acc[6][4]) {
  const int tid = threadIdx.x;
  const int wave = tid >> 6, lane = tid & 63;
  const int q = lane >> 4, r16 = lane & 15;
  f32x4 zero = {0.f, 0.f, 0.f, 0.f};
#pragma unroll
  for (int a = 0; a < 6; ++a)
#pragma unroll
    for (int b = 0; b < 4; ++b) acc[a][b] = zero;

  for (int k0 = 0; k0 < K; k0 += 64) {
    if (isf32) {
      const float* Af = (const float*)A;
#pragma unroll
      for (int i = 0; i < 3; ++i) {
        int idx = i * 256 + tid;
        int rr = idx >> 3, cg = idx & 7;
        const float* sp = Af + (m0 + rr) * (long)lda + k0 + cg * 8;
        u16x8 t;
#pragma unroll
        for (int u = 0; u < 8; ++u) t[u] = f2b(sp[u]);
        *(u16x8*)(As + rr * 64 + ((cg ^ (rr & 7)) << 3)) = t;
      }
    } else {
      const u16* Ab = (const u16*)A;
#pragma unroll
      for (int i = 0; i < 3; ++i) {
        int c = i * 256 + tid;
        int rr = c >> 3, s = c & 7;
        GLOAD_LDS16(Ab + (m0 + rr) * (long)lda + k0 + ((s ^ (rr & 7)) << 3),
                    As + c * 8);
      }
    }
#pragma unroll
    for (int i = 0; i < 8; ++i) {
      int c = i * 256 + tid;
      int rr = c >> 3, s = c & 7;
      GLOAD_LDS16(Bt + (n0 + rr) * (long)K + k0 + ((s ^ (rr & 7)) << 3),
                  Bs + c * 8);
    }
    __syncthreads();
#pragma unroll
    for (int ks = 0; ks < 64; ks += 32) {
      const int ck = q + (ks >> 3);
      bf16x8 af[6], bfv[4];
#pragma unroll
      for (int rb = 0; rb < 6; ++rb) {
        int row = rb * 16 + r16;
        af[rb] = *(const bf16x8*)(As + row * 64 + ((ck ^ (row & 7)) << 3));
      }
#pragma unroll
      for (int cb = 0; cb < 4; ++cb) {
        int row = (wave * 4 + cb) * 16 + r16;
        bfv[cb] = *(const bf16x8*)(Bs + row * 64 + ((ck ^ (row & 7)) << 3));
      }
#pragma unroll
      for (int rb = 0; rb < 6; ++rb)
#pragma unroll
        for (int cb = 0; cb < 4; ++cb)
          acc[rb][cb] = __builtin_amdgcn_mfma_f32_16x16x32_bf16(
              af[rb], bfv[cb], acc[rb][cb], 0, 0, 0);
    }
    __syncthreads();
  }
}

// ------ MFMA GEMM core, 96x128 tile (round-6, proven; single-buffer) --------
__device__ __forceinline__ void gemm_core128(const void* __restrict__ A,
                                             int lda, int isf32,
                                             const u16* __restrict__ Bt,
                                             u16* As, u16* Bs,
                                             long m0, long n0, int K,
                                             f32x4 acc[6][2]) {
  const int tid = threadIdx.x;
  const int wave = tid >> 6, lane = tid & 63;
  const int q = lane >> 4, r16 = lane & 15;
  f32x4 zero = {0.f, 0.f, 0.f, 0.f};
#pragma unroll
  for (int a = 0; a < 6; ++a)
#pragma unroll
    for (int b = 0; b < 2; ++b) acc[a][b] = zero;

  for (int k0 = 0; k0 < K; k0 += 64) {
    if (isf32) {
      const float* Af = (const float*)A;
#pragma unroll
      for (int i = 0; i < 3; ++i) {
        int idx = i * 256 + tid;
        int rr = idx >> 3, cg = idx & 7;
        const float* sp = Af + (m0 + rr) * (long)lda + k0 + cg * 8;
        u16x8 t;
#pragma unroll
        for (int u = 0; u < 8; ++u) t[u] = f2b(sp[u]);
        *(u16x8*)(As + rr * 64 + ((cg ^ (rr & 7)) << 3)) = t;
      }
    } else {
      const u16* Ab = (const u16*)A;
#pragma unroll
      for (int i = 0; i < 3; ++i) {
        int c = i * 256 + tid;
        int rr = c >> 3, s = c & 7;
        GLOAD_LDS16(Ab + (m0 + rr) * (long)lda + k0 + ((s ^ (rr & 7)) << 3),
                    As + c * 8);
      }
    }
#pragma unroll
    for (int i = 0; i < 4; ++i) {       // 128 rows x 8 chunks = 1024
      int c = i * 256 + tid;
      int rr = c >> 3, s = c & 7;
      GLOAD_LDS16(Bt + (n0 + rr) * (long)K + k0 + ((s ^ (rr & 7)) << 3),
                  Bs + c * 8);
    }
    __syncthreads();
#pragma unroll
    for (int ks = 0; ks < 64; ks += 32) {
      const int ck = q + (ks >> 3);
      bf16x8 af[6], bfv[2];
#pragma unroll
      for (int rb = 0; rb < 6; ++rb) {
        int row = rb * 16 + r16;
        af[rb] = *(const bf16x8*)(As + row * 64 + ((ck ^ (row & 7)) << 3));
      }
#pragma unroll
      for (int cb = 0; cb < 2; ++cb) {
        int row = (wave * 2 + cb) * 16 + r16;
        bfv[cb] = *(const bf16x8*)(Bs + row * 64 + ((ck ^ (row & 7)) << 3));
      }
#pragma unroll
      for (int rb = 0; rb < 6; ++rb)
#pragma unroll
        for (int cb = 0; cb < 2; ++cb)
          acc[rb][cb] = __builtin_amdgcn_mfma_f32_16x16x32_bf16(
              af[rb], bfv[cb], acc[rb][cb], 0, 0, 0);
    }
    __syncthreads();
  }
}

// XCD-chunked bijective swizzle (T1): hardware dispatches linear block id L to
// XCD L%8; remap so each XCD owns a CONTIGUOUS logical-tile range. Same-A-panel
// tiles (adjacent logical ids, n-fastest) then run on the SAME XCD's L2,
// concurrently (8 dispatch slots apart) -> deterministic single A fetch.
// Requires nwg % 8 == 0 (2048 and 6144 both qualify); bijective.
__device__ __forceinline__ int xcd_swz(int lid, int nwg) {
  return (lid & 7) * (nwg >> 3) + (lid >> 3);
}

// ---- GEMM fused with lead-mix + bias + relu (96x128 tile, 4 blk/CU) --------
template <int K>
__global__ void __launch_bounds__(256, 4) k_gemm_mix(const void* __restrict__ A,
                                                     int lda,
                                                     const u16* __restrict__ Bt,
                                                     const u16* __restrict__ bias,
                                                     u16* __restrict__ C,
                                                     const int* aflag) {
  __shared__ __align__(16) char smraw[28672];
  __shared__ float An[144];
  u16* As = (u16*)smraw;            // 96*64  = 12288 B
  u16* Bs = As + 96 * 64;           // 128*64 = 16384 B
  u16* Y = (u16*)smraw;             // 96*136 u16 = 26112 B (union, after core)
  build_anorm(An);
  f32x4 acc[6][2];
  const int nsp = gridDim.x;        // n-tiles (fastest logical axis)
  const int lid = blockIdx.x + nsp * blockIdx.y;
  const int swz = xcd_swz(lid, nsp * gridDim.y);
  const long n0 = (long)(swz % nsp) * 128;
  const long m0 = (long)(swz / nsp) * 96;
  int isf32 = aflag ? *aflag : 0;
  gemm_core128(A, lda, isf32, Bt, As, Bs, m0, n0, K, acc);
  const int tid = threadIdx.x;
  const int wave = tid >> 6, lane = tid & 63;
  const int q = lane >> 4, r16 = lane & 15;
#pragma unroll
  for (int cb = 0; cb < 2; ++cb) {
    int col = (wave * 2 + cb) * 16 + r16;    // 0..127 local
#pragma unroll
    for (int rb = 0; rb < 6; ++rb)
#pragma unroll
      for (int rr = 0; rr < 4; ++rr) {
        int row = rb * 16 + q * 4 + rr;
        Y[row * 136 + col] = f2b(acc[rb][cb][rr]);  // raw G (bias after mix)
      }
  }
  __syncthreads();
  // mix: 8 samples x 32 threads; each thread 4 local cols
  const int s = tid >> 5, cg = tid & 31;
  float bb4[4];
#pragma unroll
  for (int u = 0; u < 4; ++u) bb4[u] = b2f(bias[n0 + cg * 4 + u]);
  float xn[12][4];
#pragma unroll
  for (int j = 0; j < 12; ++j) {
    u16x4 yv = *(const u16x4*)(Y + (s * 12 + j) * 136 + cg * 4);
#pragma unroll
    for (int u = 0; u < 4; ++u) xn[j][u] = b2f(yv[u]);
  }
  const long cbase = m0 * 256;
#pragma unroll
  for (int i = 0; i < 12; ++i) {
    float o[4] = {bb4[0], bb4[1], bb4[2], bb4[3]};
    for (int j = 0; j < 12; ++j) {
      float c = An[i * 12 + j];
      if (c != 0.0f) {
#pragma unroll
        for (int u = 0; u < 4; ++u) o[u] += c * xn[j][u];
      }
    }
    u16x4 ov;
#pragma unroll
    for (int u = 0; u < 4; ++u) ov[u] = f2b(fmaxf(o[u], 0.0f));
    *(u16x4*)(C + cbase + (long)(s * 12 + i) * 256 + n0 + cg * 4) = ov;
  }
}

// ---------------- generic GEMM + bias, bf16 out ------------------------------
template <bool BIAS, int K>
__global__ void __launch_bounds__(256, 4) k_gemm(const void* __restrict__ A,
                                                 int lda,
                                                 const u16* __restrict__ Bt,
                                                 const u16* __restrict__ bias,
                                                 u16* __restrict__ C,
                                                 int Ntot,
                                                 const int* aflag) {
  __shared__ u16 As[96 * 64];
  __shared__ u16 Bs[128 * 64];
  f32x4 acc[6][2];
  const int nsp = gridDim.x;
  const int lid = blockIdx.x + nsp * blockIdx.y;
  const int swz = xcd_swz(lid, nsp * gridDim.y);
  const long n0 = (long)(swz % nsp) * 128;
  const long m0 = (long)(swz / nsp) * 96;
  int isf32 = aflag ? *aflag : 0;
  gemm_core128(A, lda, isf32, Bt, As, Bs, m0, n0, K, acc);
  const int tid = threadIdx.x;
  const int wave = tid >> 6, lane = tid & 63;
  const int q = lane >> 4, r16 = lane & 15;
#pragma unroll
  for (int cb = 0; cb < 2; ++cb) {
    long col = n0 + (wave * 2 + cb) * 16 + r16;
    float bvv = BIAS ? b2f(bias[col]) : 0.0f;
#pragma unroll
    for (int rb = 0; rb < 6; ++rb) {
#pragma unroll
      for (int rr = 0; rr < 4; ++rr) {
        long row = m0 + rb * 16 + q * 4 + rr;
        C[row * (long)Ntot + col] = f2b(acc[rb][cb][rr] + bvv);
      }
    }
  }
}

// ---------------- attention: u16x8 bulk loads (round-12-verified) ------------
__global__ void __launch_bounds__(256) k_attn(u16* __restrict__ QKV) {
  __shared__ u16 T[12 * 768];
  __shared__ float Sc[4][12][12];
  const int tid = threadIdx.x;
  const long base = (long)blockIdx.x * (12 * 768);
#pragma unroll
  for (int i = 0; i < 4; ++i) {
    int idx = i * 256 + tid;
    *(u16x8*)(T + idx * 8) = *(const u16x8*)(QKV + base + idx * 8);
  }
  {
    int off = 8192 + tid * 4;
    *(u16x4*)(T + off) = *(const u16x4*)(QKV + base + off);
  }
  __syncthreads();
  for (int p = tid; p < 576; p += 256) {
    int h = p / 144, r = p % 144, i = r / 12, j = r % 12;
    const u16* qp = T + i * 768 + h * 64;
    const u16* kp = T + j * 768 + 256 + h * 64;
    float s = 0.f;
#pragma unroll
    for (int dv = 0; dv < 8; ++dv) {
      u16x8 qv = *(const u16x8*)(qp + dv * 8);
      u16x8 kv = *(const u16x8*)(kp + dv * 8);
#pragma unroll
      for (int u = 0; u < 8; ++u) s += b2f(qv[u]) * b2f(kv[u]);
    }
    Sc[h][i][j] = s * 0.125f;
  }
  __syncthreads();
  if (tid < 48) {
    int h = tid / 12, i = tid % 12;
    float m = -1e30f;
#pragma unroll
    for (int j = 0; j < 12; ++j) m = fmaxf(m, Sc[h][i][j]);
    float e[12];
    float ssum = 0.f;
#pragma unroll
    for (int j = 0; j < 12; ++j) {
      e[j] = __expf(Sc[h][i][j] - m);
      ssum += e[j];
    }
    float inv = 1.0f / ssum;
#pragma unroll
    for (int j = 0; j < 12; ++j) Sc[h][i][j] = e[j] * inv;
  }
  __syncthreads();
  {
    int h = tid >> 6;
    int d = tid & 63;
    float vv[12];
#pragma unroll
    for (int j = 0; j < 12; ++j) vv[j] = b2f(T[j * 768 + 512 + h * 64 + d]);
#pragma unroll
    for (int i = 0; i < 12; ++i) {
      float o = 0.f;
#pragma unroll
      for (int j = 0; j < 12; ++j) o += Sc[h][i][j] * vv[j];
      QKV[base + i * 768 + h * 64 + d] = f2b(o);
    }
  }
}

// --------- residual + layernorm + lead-mix (u16x8 staging; FP order same) ----
__global__ void __launch_bounds__(256) k_resid_ln_mix(
    const u16* __restrict__ H, const u16* __restrict__ Oa,
    const u16* __restrict__ g, const u16* __restrict__ bb,
    u16* __restrict__ out) {
  __shared__ float Xn[12 * 256];
  __shared__ float An[144];
  __shared__ float mu[12], rs[12];
  build_anorm(An);
  const int tid = threadIdx.x;
  const long baseH = (long)blockIdx.x * 3072;
  const long baseO = (long)blockIdx.x * 9216;
#pragma unroll
  for (int i = 0; i < 2; ++i) {
    int idx = i * 256 + tid;        // 384 vec8 groups (Xn contents identical)
    if (idx < 384) {
      int row = idx >> 5, c8 = idx & 31;
      u16x8 hv = *(const u16x8*)(H + baseH + idx * 8);
      u16x8 ov = *(const u16x8*)(Oa + baseO + row * 768 + c8 * 8);
#pragma unroll
      for (int u = 0; u < 8; ++u) Xn[idx * 8 + u] = b2f(hv[u]) + b2f(ov[u]);
    }
  }
  __syncthreads();
  {
    int wave = tid >> 6, lane = tid & 63;
    for (int rr = wave; rr < 12; rr += 4) {
      float s = 0.f, s2 = 0.f;
#pragma unroll
      for (int u = 0; u < 4; ++u) {
        float xv = Xn[rr * 256 + u * 64 + lane];
        s += xv;
        s2 += xv * xv;
      }
#pragma unroll
      for (int off = 32; off > 0; off >>= 1) {
        s += __shfl_down(s, off, 64);
        s2 += __shfl_down(s2, off, 64);
      }
      if (lane == 0) {
        float m = s * (1.0f / 256.0f);
        float var = s2 * (1.0f / 256.0f) - m * m;
        mu[rr] = m;
        rs[rr] = rsqrtf(var + 1e-5f);
      }
    }
  }
  __syncthreads();
  {
    float gv = b2f(g[tid]);
    float bv = b2f(bb[tid]);
    float xn[12];
#pragma unroll
    for (int i = 0; i < 12; ++i) {
      float x = Xn[i * 256 + tid];
      xn[i] = (x - mu[i]) * rs[i] * gv + bv;
    }
#pragma unroll
    for (int i = 0; i < 12; ++i) {
      float o = 0.f;
#pragma unroll
      for (int j = 0; j < 12; ++j) o += An[i * 12 + j] * xn[j];
      out[baseH + i * 256 + tid] = f2b(o);
    }
  }
}

// ------- fused attention mega-kernel -- FALLBACK path (small ws), verbatim ---
__global__ void __launch_bounds__(256) k_attn_mega(
    u16* __restrict__ H, const u16* __restrict__ inw,
    const u16* __restrict__ inb, const u16* __restrict__ outw,
    const u16* __restrict__ outb, const u16* __restrict__ lng,
    const u16* __restrict__ lnb) {
  __shared__ u16 Hs[32 * 264];
  __shared__ u16 Qs[32 * 264];
  __shared__ u16 KVs[24 * 512];
  __shared__ float Sc[4][2][12][12];
  __shared__ float An[144];
  __shared__ float mu[24], rs[24];
  const int tid = threadIdx.x;
  const int wave = tid >> 6, lane = tid & 63;
  const int q = lane >> 4, r16 = lane & 15;
  build_anorm(An);
  const long base = (long)blockIdx.x * 6144;
#pragma unroll
  for (int i = 0; i < 3; ++i) {
    int idx = i * 256 + tid;
    int rr = idx >> 5, cg = idx & 31;
    *(u16x8*)(Hs + rr * 264 + cg * 8) = *(const u16x8*)(H + base + idx * 8);
  }
  {
    int rr = 24 + (tid >> 5), cg = tid & 31;
    u16x8 z = {0, 0, 0, 0, 0, 0, 0, 0};
    *(u16x8*)(Hs + rr * 264 + cg * 8) = z;
  }
  __syncthreads();
  {
    f32x4 acc[2][12];
    f32x4 zero = {0.f, 0.f, 0.f, 0.f};
#pragma unroll
    for (int rb = 0; rb < 2; ++rb)
#pragma unroll
      for (int c = 0; c < 12; ++c) acc[rb][c] = zero;
    for (int k0 = 0; k0 < 256; k0 += 32) {
      bf16x8 af[2];
#pragma unroll
      for (int rb = 0; rb < 2; ++rb)
        af[rb] = *(const bf16x8*)(Hs + (rb * 16 + r16) * 264 + k0 + q * 8);
#pragma unroll
      for (int c = 0; c < 12; ++c) {
        bf16x8 bf = *(const bf16x8*)(inw + (long)((wave * 12 + c) * 16 + r16) * 256 + k0 + q * 8);
#pragma unroll
        for (int rb = 0; rb < 2; ++rb)
          acc[rb][c] = __builtin_amdgcn_mfma_f32_16x16x32_bf16(af[rb], bf, acc[rb][c], 0, 0, 0);
      }
    }
#pragma unroll
    for (int c = 0; c < 12; ++c) {
      int col = (wave * 12 + c) * 16 + r16;
      float bv = b2f(inb[col]);
#pragma unroll
      for (int rb = 0; rb < 2; ++rb)
#pragma unroll
        for (int rr2 = 0; rr2 < 4; ++rr2) {
          int row = rb * 16 + q * 4 + rr2;
          float v = acc[rb][c][rr2] + bv;
          if (col < 256) Qs[row * 264 + col] = f2b(v);
          else if (row < 24) KVs[row * 512 + col - 256] = f2b(v);
        }
    }
  }
  __syncthreads();
  {
    int h = wave;
#pragma unroll
    for (int t = 0; t < 5; ++t) {
      int p = t * 64 + lane;
      if (p < 288) {
        int s = p / 144, r = p - s * 144, i = r / 12, j = r - i * 12;
        const u16* qp = Qs + (s * 12 + i) * 264 + h * 64;
        const u16* kp = KVs + (s * 12 + j) * 512 + h * 64;
        float dot = 0.f;
#pragma unroll
        for (int dv = 0; dv < 8; ++dv) {
          u16x8 qv = *(const u16x8*)(qp + dv * 8);
          u16x8 kv = *(const u16x8*)(kp + dv * 8);
#pragma unroll
          for (int u = 0; u < 8; ++u) dot += b2f(qv[u]) * b2f(kv[u]);
        }
        Sc[h][s][i][j] = dot * 0.125f;
      }
    }
  }
  __syncthreads();
  if (lane < 24) {
    int h = wave, s = lane / 12, i = lane - (lane / 12) * 12;
    float m = -1e30f;
#pragma unroll
    for (int j = 0; j < 12; ++j) m = fmaxf(m, Sc[h][s][i][j]);
    float e[12];
    float ssum = 0.f;
#pragma unroll
    for (int j = 0; j < 12; ++j) {
      e[j] = __expf(Sc[h][s][i][j] - m);
      ssum += e[j];
    }
    float inv = 1.0f / ssum;
#pragma unroll
    for (int j = 0; j < 12; ++j) Sc[h][s][i][j] = e[j] * inv;
  }
  __syncthreads();
  {
    int h = wave, d = lane;
    for (int si = 0; si < 24; ++si) {
      int s = si / 12;
      float o = 0.f;
#pragma unroll
      for (int j = 0; j < 12; ++j)
        o += Sc[h][s][si - s * 12][j] * b2f(KVs[(s * 12 + j) * 512 + 256 + h * 64 + d]);
      Qs[si * 264 + h * 64 + d] = f2b(o);
    }
  }
  __syncthreads();
  {
    f32x4 acc[2][4];
    f32x4 zero = {0.f, 0.f, 0.f, 0.f};
#pragma unroll
    for (int rb = 0; rb < 2; ++rb)
#pragma unroll
      for (int cb = 0; cb < 4; ++cb) acc[rb][cb] = zero;
    for (int k0 = 0; k0 < 256; k0 += 32) {
      bf16x8 af[2];
#pragma unroll
      for (int rb = 0; rb < 2; ++rb)
        af[rb] = *(const bf16x8*)(Qs + (rb * 16 + r16) * 264 + k0 + q * 8);
#pragma unroll
      for (int cb = 0; cb < 4; ++cb) {
        bf16x8 bf = *(const bf16x8*)(outw + (long)((wave * 4 + cb) * 16 + r16) * 256 + k0 + q * 8);
#pragma unroll
        for (int rb = 0; rb < 2; ++rb)
          acc[rb][cb] = __builtin_amdgcn_mfma_f32_16x16x32_bf16(af[rb], bf, acc[rb][cb], 0, 0, 0);
      }
    }
#pragma unroll
    for (int cb = 0; cb < 4; ++cb) {
      int col = (wave * 4 + cb) * 16 + r16;
      float ob = b2f(outb[col]);
#pragma unroll
      for (int rb = 0; rb < 2; ++rb)
#pragma unroll
        for (int rr2 = 0; rr2 < 4; ++rr2) {
          int row = rb * 16 + q * 4 + rr2;
          if (row < 24) {
            float x = acc[rb][cb][rr2] + ob + b2f(Hs[row * 264 + col]);
            Hs[row * 264 + col] = f2b(x);
          }
        }
    }
  }
  __syncthreads();
  {
    for (int rr2 = wave * 6; rr2 < wave * 6 + 6; ++rr2) {
      float s1 = 0.f, s2 = 0.f;
#pragma unroll
      for (int u = 0; u < 4; ++u) {
        float xv = b2f(Hs[rr2 * 264 + u * 64 + lane]);
        s1 += xv;
        s2 += xv * xv;
      }
#pragma unroll
      for (int off = 32; off > 0; off >>= 1) {
        s1 += __shfl_down(s1, off, 64);
        s2 += __shfl_down(s2, off, 64);
      }
      if (lane == 0) {
        float m = s1 * (1.0f / 256.0f);
        mu[rr2] = m;
        rs[rr2] = rsqrtf(s2 * (1.0f / 256.0f) - m * m + 1e-5f);
      }
    }
  }
  __syncthreads();
  {
    float gvv = b2f(lng[tid]);
    float bvv = b2f(lnb[tid]);
#pragma unroll
    for (int s = 0; s < 2; ++s) {
      float xn[12];
#pragma unroll
      for (int j = 0; j < 12; ++j) {
        int row = s * 12 + j;
        xn[j] = (b2f(Hs[row * 264 + tid]) - mu[row]) * rs[row] * gvv + bvv;
      }
#pragma unroll
      for (int i = 0; i < 12; ++i) {
        float o = 0.f;
#pragma unroll
        for (int j = 0; j < 12; ++j) o += An[i * 12 + j] * xn[j];
        H[base + (s * 12 + i) * 256 + tid] = f2b(o);
      }
    }
  }
}

// ---------- final GEMM + bias + attention-pooling; OUTPUT = float32 ----------
// (256,2): round-14 measured best; (256,3) in round 15 was neutral.
__global__ void __launch_bounds__(256, 2) k_gemm_pool(const u16* __restrict__ A,
                                                      const u16* __restrict__ Bt,
                                                      const u16* __restrict__ bias,
                                                      float* __restrict__ out) {
  __shared__ __align__(16) char smraw[50688];
  __shared__ float rowsum[96];
  __shared__ float wsm[96];
  u16* As = (u16*)smraw;            // 96*64
  u16* Bs = As + 96 * 64;           // 256*64  (total 45056 B < 50688)
  u16* Y = (u16*)smraw;             // 96*264 after final barrier
  f32x4 acc[6][4];
  const long m0 = (long)blockIdx.x * 96;
  gemm_core(A, 256, 0, Bt, As, Bs, m0, 0, 256, acc);
  const int tid = threadIdx.x;
  const int wave = tid >> 6, lane = tid & 63;
  const int q = lane >> 4, r16 = lane & 15;
#pragma unroll
  for (int cb = 0; cb < 4; ++cb) {
    int col = (wave * 4 + cb) * 16 + r16;
    float bvv = b2f(bias[col]);
#pragma unroll
    for (int rb = 0; rb < 6; ++rb)
#pragma unroll
      for (int rr = 0; rr < 4; ++rr) {
        int row = rb * 16 + q * 4 + rr;
        Y[row * 264 + col] = f2b(acc[rb][cb][rr] + bvv);
      }
  }
  __syncthreads();
  for (int row = wave; row < 96; row += 4) {
    float s = 0.f;
#pragma unroll
    for (int u = 0; u < 4; ++u) s += b2f(Y[row * 264 + u * 64 + lane]);
#pragma unroll
    for (int off = 32; off > 0; off >>= 1) s += __shfl_down(s, off, 64);
    if (lane == 0) rowsum[row] = s;
  }
  __syncthreads();
  if (tid < 8) {
    float m = -1e30f;
#pragma unroll
    for (int l = 0; l < 12; ++l) m = fmaxf(m, rowsum[tid * 12 + l]);
    float e[12];
    float ssum = 0.f;
#pragma unroll
    for (int l = 0; l < 12; ++l) {
      e[l] = __expf((rowsum[tid * 12 + l] - m) * (1.0f / 256.0f));
      ssum += e[l];
    }
    float inv = 1.0f / ssum;
#pragma unroll
    for (int l = 0; l < 12; ++l) wsm[tid * 12 + l] = e[l] * inv;
  }
  __syncthreads();
  {
    int s = tid >> 5, cg = tid & 31;
    float wa[8], mx[8];
#pragma unroll
    for (int u = 0; u < 8; ++u) {
      wa[u] = 0.f;
      mx[u] = -1e30f;
    }
#pragma unroll
    for (int l = 0; l < 12; ++l) {
      float w = wsm[s * 12 + l];
      u16x8 yv = *(const u16x8*)(Y + (s * 12 + l) * 264 + cg * 8);
#pragma unroll
      for (int u = 0; u < 8; ++u) {
        float y = b2f(yv[u]);
        wa[u] += w * y;
        mx[u] = fmaxf(mx[u], y);
      }
    }
    long ob = ((long)blockIdx.x * 8 + s) * 512;
#pragma unroll
    for (int u = 0; u < 8; ++u) {
      out[ob + cg * 8 + u] = wa[u];
      out[ob + 256 + cg * 8 + u] = mx[u];
    }
  }
}

extern "C" void kernel_launch(void* const* d_in, const int* in_sizes, int n_in,
                              void* d_out, int out_size, void* d_ws,
                              size_t ws_size, hipStream_t stream) {
  (void)in_sizes; (void)n_in; (void)out_size;
  const void* x    = d_in[0];
  const void* W1   = d_in[1];
  const void* b1   = d_in[2];
  const void* W2   = d_in[3];
  const void* b2   = d_in[4];
  const void* W3   = d_in[5];
  const void* b3   = d_in[6];
  const void* inw  = d_in[7];
  const void* inb  = d_in[8];
  const void* outw = d_in[9];
  const void* outb = d_in[10];
  const void* lng  = d_in[11];
  const void* lnb  = d_in[12];
  float* out = (float*)d_out;

  u16* ws16 = (u16*)d_ws;
  int* flags = (int*)d_ws;                 // flags[0]=x dtype, flags[1]=W dtype
  u16* W1T    = ws16 + 64;
  u16* W2T    = W1T + 131072;
  u16* W3T    = W2T + 65536;
  u16* inw_b  = W3T + 65536;
  u16* outw_b = inw_b + 196608;
  u16* b1b    = outw_b + 65536;
  u16* b2b    = b1b + 256;
  u16* b3b    = b2b + 256;
  u16* inbb   = b3b + 256;
  u16* outbb  = inbb + 768;
  u16* lngb   = outbb + 256;
  u16* lnbb   = lngb + 256;
  u16* BUF    = lnbb + 256;            // 25165824 elems (H2 / HL)
  u16* QKV    = BUF + 25165824L;       // 75497472 elems (pipeline A only)
  const size_t NEED_A = (size_t)(QKV + 75497472L - ws16) * 2;  // ~202.4 MB

  k_detect2<<<2, 256, 0, stream>>>(x, W1, flags);

  k_cvt_small<<<9, 256, 0, stream>>>(b1, b2, b3, inb, outb, lng, lnb, b1b,
                                     flags + 1);
  k_cvt_w<<<1024, 256, 0, stream>>>(inw, outw, inw_b, flags + 1);
  k_transpose3<<<1024, 256, 0, stream>>>(W1, W2, W3, W1T, flags + 1);

  if (ws_size >= NEED_A) {
    u16* H1 = QKV;  // QKV region is dead until the QKV projection; use as
                    // scratch so gemm_mix never writes a buffer it reads.
    // H1 = relu(A.(x@W1)+b1)   [mix fused in epilogue; XCD-chunked swizzle]
    k_gemm_mix<512><<<dim3(2, 1024), 256, 0, stream>>>(x, 512, W1T, b1b, H1, flags);
    // H2 = relu(A.(H1@W2)+b2) -> BUF
    k_gemm_mix<256><<<dim3(2, 1024), 256, 0, stream>>>(H1, 256, W2T, b2b, BUF, nullptr);
    // QKV = H2 @ in_w^T + in_b   (overwrites dead H1 scratch)
    k_gemm<true, 256><<<dim3(6, 1024), 256, 0, stream>>>(BUF, 256, inw_b, inbb, QKV, 768, nullptr);
    // attention, O -> Q slots (in place, per-block LDS-buffered)
    k_attn<<<8192, 256, 0, stream>>>(QKV);
    // O2 = O @ out_w^T + out_b -> K slots of QKV (disjoint from Q-slot reads)
    k_gemm<true, 256><<<dim3(2, 1024), 256, 0, stream>>>(QKV, 768, outw_b, outbb, QKV + 256, 768, nullptr);
    // HL = A.( LN(H2 + O2) ), in place into BUF  (round-6 FP order)
    k_resid_ln_mix<<<8192, 256, 0, stream>>>(BUF, QKV + 256, lngb, lnbb, BUF);
  } else {
    // Fallback (never taken in practice: ws has always been >= NEED_A).
    k_gemm_mix<512><<<dim3(2, 1024), 256, 0, stream>>>(x, 512, W1T, b1b, BUF, flags);
    k_gemm_mix<256><<<dim3(2, 1024), 256, 0, stream>>>(BUF, 256, W2T, b2b, BUF, nullptr);
    k_attn_mega<<<4096, 256, 0, stream>>>(BUF, inw_b, inbb, outw_b, outbb, lngb, lnbb);
  }
  // out = pool( HL@W3 + b3 )  -- float32 output
  k_gemm_pool<<<1024, 256, 0, stream>>>(BUF, W3T, b3b, out);
}